// Round 1
// baseline (879.454 us; speedup 1.0000x reference)
//
#include <hip/hip_runtime.h>

constexpr int NN = 50000;    // nodes
constexpr int NE = 1600000;  // edges
constexpr int NG = 128;      // graphs

// workspace layout (bytes); all offsets 16B-aligned
#define OFF_DEG      0            // int[50000]
#define OFF_GSUM     200000       // float[128*20]
#define OFF_GCNT     210240       // float[128]
#define ZERO_BYTES   210752
#define OFF_ROWSTART 210752       // int[50000]
#define OFF_CURSOR   410752       // int[50000]
#define OFF_ADJ      610752       // int[1600000]
#define OFF_X1       7010752      // float[50000*100] = feat@W1
#define OFF_H1       27010752     // float[50000*100] = relu layer1
#define OFF_X2       47010752     // float[50000*20]  = H1@W2
// end: 51010752 bytes (~51 MB)

// ---- in-degree histogram -------------------------------------------------
__global__ void k_deg(const int* __restrict__ dst, int* __restrict__ deg) {
    int i = blockIdx.x * blockDim.x + threadIdx.x;
    if (i < NE) atomicAdd(&deg[dst[i]], 1);
}

// ---- exclusive scan of deg -> rowstart (and cursor copy), single block ----
__global__ __launch_bounds__(1024) void k_scan(const int* __restrict__ deg,
                                               int* __restrict__ rowstart,
                                               int* __restrict__ cursor) {
    __shared__ int sums[1024];
    const int t = threadIdx.x;
    const int chunk = (NN + 1023) / 1024;   // 49
    const int lo = t * chunk;
    const int hi = min(lo + chunk, NN);
    int s = 0;
    for (int i = lo; i < hi; ++i) s += deg[i];
    sums[t] = s;
    __syncthreads();
    // Hillis-Steele inclusive scan over 1024 partials
    for (int off = 1; off < 1024; off <<= 1) {
        int v = (t >= off) ? sums[t - off] : 0;
        __syncthreads();
        sums[t] += v;
        __syncthreads();
    }
    int run = (t > 0) ? sums[t - 1] : 0;    // exclusive prefix for this chunk
    for (int i = lo; i < hi; ++i) {
        rowstart[i] = run;
        cursor[i]   = run;
        run += deg[i];
    }
}

// ---- CSR fill: adj holds src node of every in-edge, grouped by dst --------
__global__ void k_fill(const int* __restrict__ src, const int* __restrict__ dst,
                       int* __restrict__ cursor, int* __restrict__ adj) {
    int i = blockIdx.x * blockDim.x + threadIdx.x;
    if (i < NE) {
        int p = atomicAdd(&cursor[dst[i]], 1);
        adj[p] = src[i];
    }
}

// ---- X1 = feat @ W1  (50000x128 @ 128x100), no bias yet -------------------
// One wave per 8 nodes. Lane covers output cols {lane, 64+lane(<36)}.
__global__ __launch_bounds__(64) void k_gemm1(const float4* __restrict__ feat4,
                                              const float* __restrict__ W1,
                                              float* __restrict__ X1) {
    const int lane = threadIdx.x;
    const int base = blockIdx.x * 8;
    const int l2 = 64 + ((lane < 36) ? lane : 35);  // clamped; masked at store
    float acc0[8] = {0, 0, 0, 0, 0, 0, 0, 0};
    float acc1[8] = {0, 0, 0, 0, 0, 0, 0, 0};
    for (int k4 = 0; k4 < 32; ++k4) {
        float4 f[8];
#pragma unroll
        for (int i = 0; i < 8; ++i) f[i] = feat4[(base + i) * 32 + k4];
#pragma unroll
        for (int kk = 0; kk < 4; ++kk) {
            const int k = k4 * 4 + kk;
            const float w0 = W1[k * 100 + lane];
            const float w1 = W1[k * 100 + l2];
#pragma unroll
            for (int i = 0; i < 8; ++i) {
                const float fv = (kk == 0) ? f[i].x
                               : (kk == 1) ? f[i].y
                               : (kk == 2) ? f[i].z : f[i].w;
                acc0[i] += fv * w0;
                acc1[i] += fv * w1;
            }
        }
    }
#pragma unroll
    for (int i = 0; i < 8; ++i) {
        X1[(base + i) * 100 + lane] = acc0[i];
        if (lane < 36) X1[(base + i) * 100 + 64 + lane] = acc1[i];
    }
}

// ---- layer-1 aggregate: H1 = relu(where(deg>0, mean(X1[adj]), X1) + b1) ---
// Thread per (node, q), q indexes one float4 of the 100-dim row (25 per node).
__global__ void k_agg1(const float4* __restrict__ X1v, const int* __restrict__ rowstart,
                       const int* __restrict__ deg, const int* __restrict__ adj,
                       const float4* __restrict__ b1v, float4* __restrict__ H1v) {
    int tid = blockIdx.x * blockDim.x + threadIdx.x;
    if (tid >= NN * 25) return;
    const int node = tid / 25;
    const int q = tid - node * 25;
    const int rs = rowstart[node];
    const int d = deg[node];
    float ax = 0.f, ay = 0.f, az = 0.f, aw = 0.f;
    for (int i = 0; i < d; ++i) {
        const int s = adj[rs + i];          // broadcast across the 25-lane group
        const float4 v = X1v[s * 25 + q];   // contiguous 400B row per edge
        ax += v.x; ay += v.y; az += v.z; aw += v.w;
    }
    if (d > 0) {
        const float inv = 1.f / (float)d;
        ax *= inv; ay *= inv; az *= inv; aw *= inv;
    } else {
        const float4 v = X1v[node * 25 + q];
        ax = v.x; ay = v.y; az = v.z; aw = v.w;
    }
    const float4 b = b1v[q];
    float4 r;
    r.x = fmaxf(ax + b.x, 0.f);
    r.y = fmaxf(ay + b.y, 0.f);
    r.z = fmaxf(az + b.z, 0.f);
    r.w = fmaxf(aw + b.w, 0.f);
    H1v[tid] = r;   // tid == node*25+q
}

// ---- X2 = H1 @ W2  (50000x100 @ 100x20), no bias yet ----------------------
__global__ void k_gemm2(const float* __restrict__ H1, const float* __restrict__ W2,
                        float* __restrict__ X2) {
    int tid = blockIdx.x * blockDim.x + threadIdx.x;
    if (tid >= NN * 20) return;
    const int node = tid / 20;
    const int j = tid - node * 20;
    const float* h = H1 + node * 100;
    float acc = 0.f;
#pragma unroll 5
    for (int k = 0; k < 100; ++k) acc += h[k] * W2[k * 20 + j];
    X2[tid] = acc;   // coalesced: tid == node*20+j
}

// ---- layer-2 aggregate + per-graph accumulate -----------------------------
// Thread per (node, q), q indexes one float4 of the 20-dim row (5 per node).
__global__ void k_agg2(const float4* __restrict__ X2v, const int* __restrict__ rowstart,
                       const int* __restrict__ deg, const int* __restrict__ adj,
                       const float4* __restrict__ b2v, const int* __restrict__ graph_id,
                       float* __restrict__ g_sum, float* __restrict__ g_cnt) {
    int tid = blockIdx.x * blockDim.x + threadIdx.x;
    if (tid >= NN * 5) return;
    const int node = tid / 5;
    const int q = tid - node * 5;
    const int rs = rowstart[node];
    const int d = deg[node];
    float ax = 0.f, ay = 0.f, az = 0.f, aw = 0.f;
    for (int i = 0; i < d; ++i) {
        const int s = adj[rs + i];
        const float4 v = X2v[s * 5 + q];
        ax += v.x; ay += v.y; az += v.z; aw += v.w;
    }
    if (d > 0) {
        const float inv = 1.f / (float)d;
        ax *= inv; ay *= inv; az *= inv; aw *= inv;
    } else {
        const float4 v = X2v[node * 5 + q];
        ax = v.x; ay = v.y; az = v.z; aw = v.w;
    }
    const float4 b = b2v[q];
    const float hx = fmaxf(ax + b.x, 0.f);
    const float hy = fmaxf(ay + b.y, 0.f);
    const float hz = fmaxf(az + b.z, 0.f);
    const float hw = fmaxf(aw + b.w, 0.f);
    const int g = graph_id[node];
    float* gs = g_sum + g * 20 + q * 4;
    atomicAdd(gs + 0, hx);
    atomicAdd(gs + 1, hy);
    atomicAdd(gs + 2, hz);
    atomicAdd(gs + 3, hw);
    if (q == 0) atomicAdd(&g_cnt[g], 1.f);
}

// ---- final: hg = g_sum/max(cnt,1); out = relu([hg,self]@Wf1+bf1)@Wf2+bf2 --
__global__ __launch_bounds__(128) void k_final(const float* __restrict__ g_sum,
                                               const float* __restrict__ g_cnt,
                                               const float* __restrict__ self_feat,
                                               const float* __restrict__ Wf1,
                                               const float* __restrict__ bf1,
                                               const float* __restrict__ Wf2,
                                               const float* __restrict__ bf2,
                                               float* __restrict__ out) {
    const int g = threadIdx.x;  // 128 graphs, one block
    float fused[36];
    const float cnt = fmaxf(g_cnt[g], 1.f);
    const float inv = 1.f / cnt;
#pragma unroll
    for (int j = 0; j < 20; ++j) fused[j] = g_sum[g * 20 + j] * inv;
#pragma unroll
    for (int j = 0; j < 16; ++j) fused[20 + j] = self_feat[g * 16 + j];
    float o = bf2[0];
#pragma unroll
    for (int i = 0; i < 10; ++i) {
        float t = bf1[i];
#pragma unroll
        for (int k = 0; k < 36; ++k) t += fused[k] * Wf1[k * 10 + i];
        o += fmaxf(t, 0.f) * Wf2[i];
    }
    out[g] = o;
}

extern "C" void kernel_launch(void* const* d_in, const int* in_sizes, int n_in,
                              void* d_out, int out_size, void* d_ws, size_t ws_size,
                              hipStream_t stream) {
    const float* feat      = (const float*)d_in[0];
    const float* self_feat = (const float*)d_in[1];
    const int*   src       = (const int*)d_in[2];
    const int*   dst       = (const int*)d_in[3];
    const int*   graph_id  = (const int*)d_in[4];
    const float* W1        = (const float*)d_in[5];
    const float* b1        = (const float*)d_in[6];
    const float* W2        = (const float*)d_in[7];
    const float* b2        = (const float*)d_in[8];
    const float* Wf1       = (const float*)d_in[9];
    const float* bf1       = (const float*)d_in[10];
    const float* Wf2       = (const float*)d_in[11];
    const float* bf2       = (const float*)d_in[12];

    char* w = (char*)d_ws;
    int*   deg      = (int*)(w + OFF_DEG);
    float* g_sum    = (float*)(w + OFF_GSUM);
    float* g_cnt    = (float*)(w + OFF_GCNT);
    int*   rowstart = (int*)(w + OFF_ROWSTART);
    int*   cursor   = (int*)(w + OFF_CURSOR);
    int*   adj      = (int*)(w + OFF_ADJ);
    float* X1       = (float*)(w + OFF_X1);
    float* H1       = (float*)(w + OFF_H1);
    float* X2       = (float*)(w + OFF_X2);

    hipMemsetAsync(w, 0, ZERO_BYTES, stream);  // deg + g_sum + g_cnt

    k_deg<<<(NE + 255) / 256, 256, 0, stream>>>(dst, deg);
    k_scan<<<1, 1024, 0, stream>>>(deg, rowstart, cursor);
    k_fill<<<(NE + 255) / 256, 256, 0, stream>>>(src, dst, cursor, adj);
    k_gemm1<<<NN / 8, 64, 0, stream>>>((const float4*)feat, W1, X1);
    k_agg1<<<(NN * 25 + 255) / 256, 256, 0, stream>>>((const float4*)X1, rowstart, deg,
                                                      adj, (const float4*)b1, (float4*)H1);
    k_gemm2<<<(NN * 20 + 255) / 256, 256, 0, stream>>>(H1, W2, X2);
    k_agg2<<<(NN * 5 + 255) / 256, 256, 0, stream>>>((const float4*)X2, rowstart, deg,
                                                     adj, (const float4*)b2, graph_id,
                                                     g_sum, g_cnt);
    k_final<<<1, 128, 0, stream>>>(g_sum, g_cnt, self_feat, Wf1, bf1, Wf2, bf2,
                                   (float*)d_out);
}

// Round 2
// 761.785 us; speedup vs baseline: 1.1545x; 1.1545x over previous
//
#include <hip/hip_runtime.h>

constexpr int NN = 50000;    // nodes
constexpr int NE = 1600000;  // edges
constexpr int NG = 128;      // graphs

// workspace layout (bytes); all offsets 16B-aligned
#define OFF_DEG      0            // int[50000]
#define OFF_GSUM     200000       // float[128*20]
#define OFF_GCNT     210240       // float[128]
#define ZERO_BYTES   210752
#define OFF_ROWSTART 210752       // int[50000]
#define OFF_CURSOR   410752       // int[50000]
#define OFF_ADJ      610752       // int[1600000]
#define OFF_X1       7010752      // float[50000*100] = feat@W1
#define OFF_H1       27010752     // float[50000*100] = relu layer1
#define OFF_X2       47010752     // float[50000*20]  = H1@W2
// end: 51010752 bytes (~51 MB)

// ---- in-degree histogram -------------------------------------------------
__global__ void k_deg(const int* __restrict__ dst, int* __restrict__ deg) {
    int i = blockIdx.x * blockDim.x + threadIdx.x;
    if (i < NE) atomicAdd(&deg[dst[i]], 1);
}

// ---- exclusive scan of deg -> rowstart (and cursor copy), single block ----
__global__ __launch_bounds__(1024) void k_scan(const int* __restrict__ deg,
                                               int* __restrict__ rowstart,
                                               int* __restrict__ cursor) {
    __shared__ int sums[1024];
    const int t = threadIdx.x;
    const int chunk = (NN + 1023) / 1024;   // 49
    const int lo = t * chunk;
    const int hi = min(lo + chunk, NN);
    int s = 0;
    for (int i = lo; i < hi; ++i) s += deg[i];
    sums[t] = s;
    __syncthreads();
    // Hillis-Steele inclusive scan over 1024 partials
    for (int off = 1; off < 1024; off <<= 1) {
        int v = (t >= off) ? sums[t - off] : 0;
        __syncthreads();
        sums[t] += v;
        __syncthreads();
    }
    int run = (t > 0) ? sums[t - 1] : 0;    // exclusive prefix for this chunk
    for (int i = lo; i < hi; ++i) {
        rowstart[i] = run;
        cursor[i]   = run;
        run += deg[i];
    }
}

// ---- CSR fill: adj holds src node of every in-edge, grouped by dst --------
__global__ void k_fill(const int* __restrict__ src, const int* __restrict__ dst,
                       int* __restrict__ cursor, int* __restrict__ adj) {
    int i = blockIdx.x * blockDim.x + threadIdx.x;
    if (i < NE) {
        int p = atomicAdd(&cursor[dst[i]], 1);
        adj[p] = src[i];
    }
}

// ---- X1 = feat @ W1  (50000x128 @ 128x100), no bias yet -------------------
// Register-tiled: thread = 4 nodes x 4 cols (16 acc), K blocked by 4 so both
// operands are float4 loads. Block 256 (250 active): cg=t%25 (col quad),
// nq=t/25 (node quad 0..9) -> 40 nodes/block, grid 1250.
__global__ __launch_bounds__(256) void k_gemm1(const float4* __restrict__ feat4,
                                               const float* __restrict__ W1,
                                               float* __restrict__ X1) {
    const int t = threadIdx.x;
    if (t >= 250) return;
    const int cg = t % 25;            // cols [4cg, 4cg+4)
    const int nq = t / 25;            // node quad within block
    const int node0 = blockIdx.x * 40 + nq * 4;
    const int col0 = cg * 4;

    float acc[4][4];
#pragma unroll
    for (int i = 0; i < 4; ++i)
#pragma unroll
        for (int j = 0; j < 4; ++j) acc[i][j] = 0.f;

    for (int k4 = 0; k4 < 32; ++k4) {
        float4 f[4];
#pragma unroll
        for (int i = 0; i < 4; ++i) f[i] = feat4[(node0 + i) * 32 + k4];
        float4 wr[4];
#pragma unroll
        for (int kk = 0; kk < 4; ++kk)
            wr[kk] = *(const float4*)(W1 + (k4 * 4 + kk) * 100 + col0);
#pragma unroll
        for (int kk = 0; kk < 4; ++kk) {
#pragma unroll
            for (int i = 0; i < 4; ++i) {
                const float fv = (kk == 0) ? f[i].x
                               : (kk == 1) ? f[i].y
                               : (kk == 2) ? f[i].z : f[i].w;
                acc[i][0] += fv * wr[kk].x;
                acc[i][1] += fv * wr[kk].y;
                acc[i][2] += fv * wr[kk].z;
                acc[i][3] += fv * wr[kk].w;
            }
        }
    }
#pragma unroll
    for (int i = 0; i < 4; ++i) {
        float4 r;
        r.x = acc[i][0]; r.y = acc[i][1]; r.z = acc[i][2]; r.w = acc[i][3];
        *(float4*)(X1 + (node0 + i) * 100 + col0) = r;
    }
}

// ---- layer-1 aggregate: H1 = relu(where(deg>0, mean(X1[adj]), X1) + b1) ---
// Thread per (node, q), q indexes one float4 of the 100-dim row (25 per node).
__global__ void k_agg1(const float4* __restrict__ X1v, const int* __restrict__ rowstart,
                       const int* __restrict__ deg, const int* __restrict__ adj,
                       const float4* __restrict__ b1v, float4* __restrict__ H1v) {
    int tid = blockIdx.x * blockDim.x + threadIdx.x;
    if (tid >= NN * 25) return;
    const int node = tid / 25;
    const int q = tid - node * 25;
    const int rs = rowstart[node];
    const int d = deg[node];
    float ax = 0.f, ay = 0.f, az = 0.f, aw = 0.f;
    for (int i = 0; i < d; ++i) {
        const int s = adj[rs + i];          // broadcast across the 25-lane group
        const float4 v = X1v[s * 25 + q];   // contiguous 400B row per edge
        ax += v.x; ay += v.y; az += v.z; aw += v.w;
    }
    if (d > 0) {
        const float inv = 1.f / (float)d;
        ax *= inv; ay *= inv; az *= inv; aw *= inv;
    } else {
        const float4 v = X1v[node * 25 + q];
        ax = v.x; ay = v.y; az = v.z; aw = v.w;
    }
    const float4 b = b1v[q];
    float4 r;
    r.x = fmaxf(ax + b.x, 0.f);
    r.y = fmaxf(ay + b.y, 0.f);
    r.z = fmaxf(az + b.z, 0.f);
    r.w = fmaxf(aw + b.w, 0.f);
    H1v[tid] = r;   // tid == node*25+q
}

// ---- X2 = H1 @ W2  (50000x100 @ 100x20), no bias yet ----------------------
__global__ void k_gemm2(const float* __restrict__ H1, const float* __restrict__ W2,
                        float* __restrict__ X2) {
    int tid = blockIdx.x * blockDim.x + threadIdx.x;
    if (tid >= NN * 20) return;
    const int node = tid / 20;
    const int j = tid - node * 20;
    const float* h = H1 + node * 100;
    float acc = 0.f;
#pragma unroll 5
    for (int k = 0; k < 100; ++k) acc += h[k] * W2[k * 20 + j];
    X2[tid] = acc;   // coalesced: tid == node*20+j
}

// ---- layer-2 aggregate + per-graph accumulate -----------------------------
// Thread per (node, q), q indexes one float4 of the 20-dim row (5 per node).
__global__ void k_agg2(const float4* __restrict__ X2v, const int* __restrict__ rowstart,
                       const int* __restrict__ deg, const int* __restrict__ adj,
                       const float4* __restrict__ b2v, const int* __restrict__ graph_id,
                       float* __restrict__ g_sum, float* __restrict__ g_cnt) {
    int tid = blockIdx.x * blockDim.x + threadIdx.x;
    if (tid >= NN * 5) return;
    const int node = tid / 5;
    const int q = tid - node * 5;
    const int rs = rowstart[node];
    const int d = deg[node];
    float ax = 0.f, ay = 0.f, az = 0.f, aw = 0.f;
    for (int i = 0; i < d; ++i) {
        const int s = adj[rs + i];
        const float4 v = X2v[s * 5 + q];
        ax += v.x; ay += v.y; az += v.z; aw += v.w;
    }
    if (d > 0) {
        const float inv = 1.f / (float)d;
        ax *= inv; ay *= inv; az *= inv; aw *= inv;
    } else {
        const float4 v = X2v[node * 5 + q];
        ax = v.x; ay = v.y; az = v.z; aw = v.w;
    }
    const float4 b = b2v[q];
    const float hx = fmaxf(ax + b.x, 0.f);
    const float hy = fmaxf(ay + b.y, 0.f);
    const float hz = fmaxf(az + b.z, 0.f);
    const float hw = fmaxf(aw + b.w, 0.f);
    const int g = graph_id[node];
    float* gs = g_sum + g * 20 + q * 4;
    atomicAdd(gs + 0, hx);
    atomicAdd(gs + 1, hy);
    atomicAdd(gs + 2, hz);
    atomicAdd(gs + 3, hw);
    if (q == 0) atomicAdd(&g_cnt[g], 1.f);
}

// ---- final: hg = g_sum/max(cnt,1); out = relu([hg,self]@Wf1+bf1)@Wf2+bf2 --
__global__ __launch_bounds__(128) void k_final(const float* __restrict__ g_sum,
                                               const float* __restrict__ g_cnt,
                                               const float* __restrict__ self_feat,
                                               const float* __restrict__ Wf1,
                                               const float* __restrict__ bf1,
                                               const float* __restrict__ Wf2,
                                               const float* __restrict__ bf2,
                                               float* __restrict__ out) {
    const int g = threadIdx.x;  // 128 graphs, one block
    float fused[36];
    const float cnt = fmaxf(g_cnt[g], 1.f);
    const float inv = 1.f / cnt;
#pragma unroll
    for (int j = 0; j < 20; ++j) fused[j] = g_sum[g * 20 + j] * inv;
#pragma unroll
    for (int j = 0; j < 16; ++j) fused[20 + j] = self_feat[g * 16 + j];
    float o = bf2[0];
#pragma unroll
    for (int i = 0; i < 10; ++i) {
        float t = bf1[i];
#pragma unroll
        for (int k = 0; k < 36; ++k) t += fused[k] * Wf1[k * 10 + i];
        o += fmaxf(t, 0.f) * Wf2[i];
    }
    out[g] = o;
}

extern "C" void kernel_launch(void* const* d_in, const int* in_sizes, int n_in,
                              void* d_out, int out_size, void* d_ws, size_t ws_size,
                              hipStream_t stream) {
    const float* feat      = (const float*)d_in[0];
    const float* self_feat = (const float*)d_in[1];
    const int*   src       = (const int*)d_in[2];
    const int*   dst       = (const int*)d_in[3];
    const int*   graph_id  = (const int*)d_in[4];
    const float* W1        = (const float*)d_in[5];
    const float* b1        = (const float*)d_in[6];
    const float* W2        = (const float*)d_in[7];
    const float* b2        = (const float*)d_in[8];
    const float* Wf1       = (const float*)d_in[9];
    const float* bf1       = (const float*)d_in[10];
    const float* Wf2       = (const float*)d_in[11];
    const float* bf2       = (const float*)d_in[12];

    char* w = (char*)d_ws;
    int*   deg      = (int*)(w + OFF_DEG);
    float* g_sum    = (float*)(w + OFF_GSUM);
    float* g_cnt    = (float*)(w + OFF_GCNT);
    int*   rowstart = (int*)(w + OFF_ROWSTART);
    int*   cursor   = (int*)(w + OFF_CURSOR);
    int*   adj      = (int*)(w + OFF_ADJ);
    float* X1       = (float*)(w + OFF_X1);
    float* H1       = (float*)(w + OFF_H1);
    float* X2       = (float*)(w + OFF_X2);

    hipMemsetAsync(w, 0, ZERO_BYTES, stream);  // deg + g_sum + g_cnt

    k_deg<<<(NE + 255) / 256, 256, 0, stream>>>(dst, deg);
    k_scan<<<1, 1024, 0, stream>>>(deg, rowstart, cursor);
    k_fill<<<(NE + 255) / 256, 256, 0, stream>>>(src, dst, cursor, adj);
    k_gemm1<<<1250, 256, 0, stream>>>((const float4*)feat, W1, X1);
    k_agg1<<<(NN * 25 + 255) / 256, 256, 0, stream>>>((const float4*)X1, rowstart, deg,
                                                      adj, (const float4*)b1, (float4*)H1);
    k_gemm2<<<(NN * 20 + 255) / 256, 256, 0, stream>>>(H1, W2, X2);
    k_agg2<<<(NN * 5 + 255) / 256, 256, 0, stream>>>((const float4*)X2, rowstart, deg,
                                                     adj, (const float4*)b2, graph_id,
                                                     g_sum, g_cnt);
    k_final<<<1, 128, 0, stream>>>(g_sum, g_cnt, self_feat, Wf1, bf1, Wf2, bf2,
                                   (float*)d_out);
}